// Round 2
// baseline (1414.361 us; speedup 1.0000x reference)
//
#include <hip/hip_runtime.h>

#define D 64

// ---------------------------------------------------------------------------
// out[0:nq*64]        = user_w[user_idx[q]][d]      (layer-0 user contribution)
// out[nq*64:2*nq*64]  = item_w[item_idx[q]][d]      (layer-0 item contribution)
// ---------------------------------------------------------------------------
__global__ __launch_bounds__(256) void k_gather_init(
    const float* __restrict__ uw, const float* __restrict__ iw,
    const int* __restrict__ ui, const int* __restrict__ ii,
    float* __restrict__ out, int nq)
{
    int t = blockIdx.x * 256 + threadIdx.x;
    int total = nq * D;
    if (t < total) {
        int q = t >> 6, d = t & 63;
        out[t] = uw[ui[q] * D + d];
    } else if (t < 2 * total) {
        int u = t - total;
        int q = u >> 6, d = u & 63;
        out[t] = iw[ii[q] * D + d];
    }
}

// out += src[gathered node], optionally scaled (final layer folds the /4)
__global__ __launch_bounds__(256) void k_gather_acc(
    const float* __restrict__ src,
    const int* __restrict__ ui, const int* __restrict__ ii,
    int n_users, float* __restrict__ out, int nq, float scale)
{
    int t = blockIdx.x * 256 + threadIdx.x;
    int total = nq * D;
    if (t < total) {
        int q = t >> 6, d = t & 63;
        int node = ui[q];
        out[t] = (out[t] + src[node * D + d]) * scale;
    } else if (t < 2 * total) {
        int u = t - total;
        int q = u >> 6, d = u & 63;
        int node = n_users + ii[q];
        out[t] = (out[t] + src[node * D + d]) * scale;
    }
}

// Layer-0 SpMM: source rows come from the (virtually concatenated) embedding
// tables. One wave per edge, lane = dim. dst must be pre-zeroed.
__global__ __launch_bounds__(256) void k_spmm_l0(
    const float* __restrict__ vals, const int* __restrict__ rows,
    const int* __restrict__ cols,
    const float* __restrict__ uw, const float* __restrict__ iw, int n_users,
    float* __restrict__ dst, int n_edges)
{
    int total = n_edges * D;                 // 128M < 2^31, int is fine
    int stride = gridDim.x * 256;
    for (int t = blockIdx.x * 256 + threadIdx.x; t < total; t += stride) {
        int e = t >> 6, d = t & 63;
        float v = vals[e];
        int c = cols[e], r = rows[e];
        float x = (c < n_users) ? uw[c * D + d] : iw[(c - n_users) * D + d];
        atomicAdd(dst + r * D + d, v * x);
    }
}

// General SpMM: dst[r] += val * src[c].  dst must be pre-zeroed.
__global__ __launch_bounds__(256) void k_spmm(
    const float* __restrict__ vals, const int* __restrict__ rows,
    const int* __restrict__ cols,
    const float* __restrict__ src, float* __restrict__ dst, int n_edges)
{
    int total = n_edges * D;
    int stride = gridDim.x * 256;
    for (int t = blockIdx.x * 256 + threadIdx.x; t < total; t += stride) {
        int e = t >> 6, d = t & 63;
        float v = vals[e];
        int c = cols[e], r = rows[e];
        atomicAdd(dst + r * D + d, v * src[c * D + d]);
    }
}

extern "C" void kernel_launch(void* const* d_in, const int* in_sizes, int n_in,
                              void* d_out, int out_size, void* d_ws, size_t ws_size,
                              hipStream_t stream) {
    const float* uw   = (const float*)d_in[0];
    const float* iw   = (const float*)d_in[1];
    const float* vals = (const float*)d_in[2];
    const int*   rows = (const int*)d_in[3];
    const int*   cols = (const int*)d_in[4];
    const int*   ui   = (const int*)d_in[5];
    const int*   ii   = (const int*)d_in[6];
    float* out = (float*)d_out;

    const int n_users = in_sizes[0] / D;
    const int n_items = in_sizes[1] / D;
    const int n_nodes = n_users + n_items;
    const int n_edges = in_sizes[2];
    const int nq      = in_sizes[5];

    const size_t buf_elems = (size_t)n_nodes * D;      // 19.2M floats
    float* bufA = (float*)d_ws;
    float* bufB = bufA + buf_elems;

    // zero both ping-pong buffers (ws is poisoned 0xAA before every launch)
    hipMemsetAsync(bufA, 0, 2 * buf_elems * sizeof(float), stream);

    const int gq = (2 * nq * D + 255) / 256;           // gather kernels
    const int gs = 8192;                               // spmm grid (grid-stride)

    // layer 0 contribution straight from the embedding tables
    k_gather_init<<<gq, 256, 0, stream>>>(uw, iw, ui, ii, out, nq);

    // layer 1: emb -> bufA
    k_spmm_l0<<<gs, 256, 0, stream>>>(vals, rows, cols, uw, iw, n_users, bufA, n_edges);
    k_gather_acc<<<gq, 256, 0, stream>>>(bufA, ui, ii, n_users, out, nq, 1.0f);

    // layer 2: bufA -> bufB
    k_spmm<<<gs, 256, 0, stream>>>(vals, rows, cols, bufA, bufB, n_edges);
    k_gather_acc<<<gq, 256, 0, stream>>>(bufB, ui, ii, n_users, out, nq, 1.0f);

    // layer 3: bufB -> bufA (re-zero bufA first; its data is already consumed)
    hipMemsetAsync(bufA, 0, buf_elems * sizeof(float), stream);
    k_spmm<<<gs, 256, 0, stream>>>(vals, rows, cols, bufB, bufA, n_edges);
    k_gather_acc<<<gq, 256, 0, stream>>>(bufA, ui, ii, n_users, out, nq, 0.25f);
}

// Round 3
// 557.297 us; speedup vs baseline: 2.5379x; 2.5379x over previous
//
#include <hip/hip_runtime.h>

#define D 64

// ============================ common small kernels ==========================

__global__ __launch_bounds__(256) void k_gather_init(
    const float* __restrict__ uw, const float* __restrict__ iw,
    const int* __restrict__ ui, const int* __restrict__ ii,
    float* __restrict__ out, int nq)
{
    int t = blockIdx.x * 256 + threadIdx.x;
    int total = nq * D;
    if (t < total) {
        int q = t >> 6, d = t & 63;
        out[t] = uw[ui[q] * D + d];
    } else if (t < 2 * total) {
        int u = t - total;
        int q = u >> 6, d = u & 63;
        out[t] = iw[ii[q] * D + d];
    }
}

__global__ __launch_bounds__(256) void k_gather_acc(
    const float* __restrict__ src,
    const int* __restrict__ ui, const int* __restrict__ ii,
    int n_users, float* __restrict__ out, int nq, float scale)
{
    int t = blockIdx.x * 256 + threadIdx.x;
    int total = nq * D;
    if (t < total) {
        int q = t >> 6, d = t & 63;
        int node = ui[q];
        out[t] = (out[t] + src[node * D + d]) * scale;
    } else if (t < 2 * total) {
        int u = t - total;
        int q = u >> 6, d = u & 63;
        int node = n_users + ii[q];
        out[t] = (out[t] + src[node * D + d]) * scale;
    }
}

// ============================== CSR build ===================================

__global__ __launch_bounds__(256) void k_count(
    const int* __restrict__ rows, int* __restrict__ cnt, int ne)
{
    int e = blockIdx.x * 256 + threadIdx.x;
    if (e < ne) atomicAdd(&cnt[rows[e]], 1);
}

// block-level exclusive scan over chunks of 1024, emit block sums
__global__ __launch_bounds__(1024) void k_scan1(
    const int* __restrict__ cnt, int* __restrict__ rstart,
    int* __restrict__ bsum, int n)
{
    __shared__ int s[1024];
    int t = threadIdx.x, i = blockIdx.x * 1024 + t;
    int v = (i < n) ? cnt[i] : 0;
    s[t] = v; __syncthreads();
    for (int off = 1; off < 1024; off <<= 1) {
        int x = (t >= off) ? s[t - off] : 0;
        __syncthreads();
        s[t] += x;
        __syncthreads();
    }
    if (i < n) rstart[i] = s[t] - v;             // exclusive within block
    if (t == 1023) bsum[blockIdx.x] = s[t];      // block total
}

// exclusive scan of the (<=1024) block sums, in place
__global__ __launch_bounds__(1024) void k_scan2(int* __restrict__ bsum, int nb)
{
    __shared__ int s[1024];
    int t = threadIdx.x;
    int v = (t < nb) ? bsum[t] : 0;
    s[t] = v; __syncthreads();
    for (int off = 1; off < 1024; off <<= 1) {
        int x = (t >= off) ? s[t - off] : 0;
        __syncthreads();
        s[t] += x;
        __syncthreads();
    }
    if (t < nb) bsum[t] = s[t] - v;
}

__global__ __launch_bounds__(1024) void k_scan3(
    int* __restrict__ rstart, const int* __restrict__ bsum, int n)
{
    int i = blockIdx.x * 1024 + threadIdx.x;
    if (i < n) rstart[i] += bsum[blockIdx.x];
}

__global__ __launch_bounds__(256) void k_scatter(
    const float* __restrict__ vals, const int* __restrict__ rows,
    const int* __restrict__ cols, const int* __restrict__ rstart,
    int* __restrict__ fill, int* __restrict__ ccol, float* __restrict__ cval,
    int ne)
{
    int e = blockIdx.x * 256 + threadIdx.x;
    if (e < ne) {
        int r = rows[e];
        int slot = atomicAdd(&fill[r], 1);
        int p = rstart[r] + slot;
        ccol[p] = cols[e];
        cval[p] = vals[e];
    }
}

// ============================== CSR SpMM ====================================
// 16 lanes per row (float4 per lane), 16 rows per 256-thread block.
// src is addressed as virtual concat: c < n_users ? srcu[c] : srci[c-n_users].
// For an already-concatenated buffer pass srcu=buf, srci=buf+n_users*D.
__global__ __launch_bounds__(256) void k_spmm_csr(
    const int* __restrict__ rstart, const int* __restrict__ cnt,
    const int* __restrict__ ccol, const float* __restrict__ cval,
    const float* __restrict__ srcu, const float* __restrict__ srci,
    int n_users, float* __restrict__ dst, int n_nodes)
{
    int lane16 = threadIdx.x & 15;
    int row = blockIdx.x * 16 + (threadIdx.x >> 4);
    if (row >= n_nodes) return;

    int s = rstart[row], dg = cnt[row];
    float4 a0 = {0, 0, 0, 0}, a1 = {0, 0, 0, 0};
    int j = 0;
    for (; j + 1 < dg; j += 2) {
        int   c0 = ccol[s + j],     c1 = ccol[s + j + 1];
        float v0 = cval[s + j],     v1 = cval[s + j + 1];
        const float* p0 = (c0 < n_users) ? &srcu[(size_t)c0 * D] : &srci[(size_t)(c0 - n_users) * D];
        const float* p1 = (c1 < n_users) ? &srcu[(size_t)c1 * D] : &srci[(size_t)(c1 - n_users) * D];
        float4 x0 = ((const float4*)p0)[lane16];
        float4 x1 = ((const float4*)p1)[lane16];
        a0.x += v0 * x0.x; a0.y += v0 * x0.y; a0.z += v0 * x0.z; a0.w += v0 * x0.w;
        a1.x += v1 * x1.x; a1.y += v1 * x1.y; a1.z += v1 * x1.z; a1.w += v1 * x1.w;
    }
    if (j < dg) {
        int c0 = ccol[s + j]; float v0 = cval[s + j];
        const float* p0 = (c0 < n_users) ? &srcu[(size_t)c0 * D] : &srci[(size_t)(c0 - n_users) * D];
        float4 x0 = ((const float4*)p0)[lane16];
        a0.x += v0 * x0.x; a0.y += v0 * x0.y; a0.z += v0 * x0.z; a0.w += v0 * x0.w;
    }
    a0.x += a1.x; a0.y += a1.y; a0.z += a1.z; a0.w += a1.w;
    ((float4*)&dst[(size_t)row * D])[lane16] = a0;
}

// ======================= layer-3: per-query CSR walk ========================
// out[q] = (out[q](layers 0..2) + sum_{edges of node} val*src[col]) * 0.25
__global__ __launch_bounds__(256) void k_final(
    const int* __restrict__ rstart, const int* __restrict__ cnt,
    const int* __restrict__ ccol, const float* __restrict__ cval,
    const float* __restrict__ src,
    const int* __restrict__ ui, const int* __restrict__ ii,
    int n_users, float* __restrict__ out, int nq, float scale)
{
    int lane16 = threadIdx.x & 15;
    int q = blockIdx.x * 16 + (threadIdx.x >> 4);
    if (q >= 2 * nq) return;
    int node = (q < nq) ? ui[q] : n_users + ii[q - nq];

    int s = rstart[node], dg = cnt[node];
    float4 a0 = ((const float4*)&out[(size_t)q * D])[lane16];
    for (int j = 0; j < dg; ++j) {
        int c = ccol[s + j]; float v = cval[s + j];
        float4 x = ((const float4*)&src[(size_t)c * D])[lane16];
        a0.x += v * x.x; a0.y += v * x.y; a0.z += v * x.z; a0.w += v * x.w;
    }
    a0.x *= scale; a0.y *= scale; a0.z *= scale; a0.w *= scale;
    ((float4*)&out[(size_t)q * D])[lane16] = a0;
}

// ===================== fallback (round-2 atomic path) =======================

__global__ __launch_bounds__(256) void k_spmm_l0(
    const float* __restrict__ vals, const int* __restrict__ rows,
    const int* __restrict__ cols,
    const float* __restrict__ uw, const float* __restrict__ iw, int n_users,
    float* __restrict__ dst, int n_edges)
{
    int total = n_edges * D;
    int stride = gridDim.x * 256;
    for (int t = blockIdx.x * 256 + threadIdx.x; t < total; t += stride) {
        int e = t >> 6, d = t & 63;
        float v = vals[e];
        int c = cols[e], r = rows[e];
        float x = (c < n_users) ? uw[c * D + d] : iw[(c - n_users) * D + d];
        atomicAdd(dst + r * D + d, v * x);
    }
}

__global__ __launch_bounds__(256) void k_spmm(
    const float* __restrict__ vals, const int* __restrict__ rows,
    const int* __restrict__ cols,
    const float* __restrict__ src, float* __restrict__ dst, int n_edges)
{
    int total = n_edges * D;
    int stride = gridDim.x * 256;
    for (int t = blockIdx.x * 256 + threadIdx.x; t < total; t += stride) {
        int e = t >> 6, d = t & 63;
        float v = vals[e];
        int c = cols[e], r = rows[e];
        atomicAdd(dst + r * D + d, v * src[c * D + d]);
    }
}

// ============================================================================

extern "C" void kernel_launch(void* const* d_in, const int* in_sizes, int n_in,
                              void* d_out, int out_size, void* d_ws, size_t ws_size,
                              hipStream_t stream) {
    const float* uw   = (const float*)d_in[0];
    const float* iw   = (const float*)d_in[1];
    const float* vals = (const float*)d_in[2];
    const int*   rows = (const int*)d_in[3];
    const int*   cols = (const int*)d_in[4];
    const int*   ui   = (const int*)d_in[5];
    const int*   ii   = (const int*)d_in[6];
    float* out = (float*)d_out;

    const int n_users = in_sizes[0] / D;
    const int n_items = in_sizes[1] / D;
    const int n_nodes = n_users + n_items;
    const int n_edges = in_sizes[2];
    const int nq      = in_sizes[5];

    const size_t buf_elems = (size_t)n_nodes * D;

    // ---- workspace carve ----
    // bufA | bufB | cnt | rstart | fill | bsum(4096) | ccol | cval
    size_t off = 0;
    float* bufA   = (float*)((char*)d_ws + off); off += buf_elems * 4;
    float* bufB   = (float*)((char*)d_ws + off); off += buf_elems * 4;
    int*   cnt    = (int*)  ((char*)d_ws + off); off += (size_t)n_nodes * 4;
    int*   rstart = (int*)  ((char*)d_ws + off); off += (size_t)n_nodes * 4;
    int*   fill   = (int*)  ((char*)d_ws + off); off += (size_t)n_nodes * 4;
    int*   bsum   = (int*)  ((char*)d_ws + off); off += 4096 * 4;
    int*   ccol   = (int*)  ((char*)d_ws + off); off += (size_t)n_edges * 4;
    float* cval   = (float*)((char*)d_ws + off); off += (size_t)n_edges * 4;

    const int nblk_scan = (n_nodes + 1023) / 1024;   // 293 for 300k nodes
    const int gq = (2 * nq * D + 255) / 256;
    const bool csr_ok = (off <= ws_size) && (nblk_scan <= 1024);

    if (csr_ok) {
        // ---- CSR build (amortized over 3 SpMM uses) ----
        hipMemsetAsync(cnt, 0, (size_t)n_nodes * 4, stream);
        hipMemsetAsync(fill, 0, (size_t)n_nodes * 4, stream);
        k_count<<<(n_edges + 255) / 256, 256, 0, stream>>>(rows, cnt, n_edges);
        k_scan1<<<nblk_scan, 1024, 0, stream>>>(cnt, rstart, bsum, n_nodes);
        k_scan2<<<1, 1024, 0, stream>>>(bsum, nblk_scan);
        k_scan3<<<nblk_scan, 1024, 0, stream>>>(rstart, bsum, n_nodes);
        k_scatter<<<(n_edges + 255) / 256, 256, 0, stream>>>(
            vals, rows, cols, rstart, fill, ccol, cval, n_edges);

        // ---- layer 0 gather ----
        k_gather_init<<<gq, 256, 0, stream>>>(uw, iw, ui, ii, out, nq);

        const int gs = (n_nodes + 15) / 16;
        // ---- layer 1: emb -> bufA ----
        k_spmm_csr<<<gs, 256, 0, stream>>>(rstart, cnt, ccol, cval,
                                           uw, iw, n_users, bufA, n_nodes);
        k_gather_acc<<<gq, 256, 0, stream>>>(bufA, ui, ii, n_users, out, nq, 1.0f);

        // ---- layer 2: bufA -> bufB ----
        k_spmm_csr<<<gs, 256, 0, stream>>>(rstart, cnt, ccol, cval,
                                           bufA, bufA + (size_t)n_users * D,
                                           n_users, bufB, n_nodes);
        k_gather_acc<<<gq, 256, 0, stream>>>(bufB, ui, ii, n_users, out, nq, 1.0f);

        // ---- layer 3: per-query only ----
        k_final<<<(2 * nq + 15) / 16, 256, 0, stream>>>(
            rstart, cnt, ccol, cval, bufB, ui, ii, n_users, out, nq, 0.25f);
    } else {
        // ---- fallback: round-2 atomic path ----
        hipMemsetAsync(bufA, 0, 2 * buf_elems * 4, stream);
        const int gs = 8192;
        k_gather_init<<<gq, 256, 0, stream>>>(uw, iw, ui, ii, out, nq);
        k_spmm_l0<<<gs, 256, 0, stream>>>(vals, rows, cols, uw, iw, n_users, bufA, n_edges);
        k_gather_acc<<<gq, 256, 0, stream>>>(bufA, ui, ii, n_users, out, nq, 1.0f);
        k_spmm<<<gs, 256, 0, stream>>>(vals, rows, cols, bufA, bufB, n_edges);
        k_gather_acc<<<gq, 256, 0, stream>>>(bufB, ui, ii, n_users, out, nq, 1.0f);
        hipMemsetAsync(bufA, 0, buf_elems * 4, stream);
        k_spmm<<<gs, 256, 0, stream>>>(vals, rows, cols, bufB, bufA, n_edges);
        k_gather_acc<<<gq, 256, 0, stream>>>(bufA, ui, ii, n_users, out, nq, 0.25f);
    }
}

// Round 4
// 505.749 us; speedup vs baseline: 2.7966x; 1.1019x over previous
//
#include <hip/hip_runtime.h>

#define D 64

// ============================ common small kernels ==========================

__global__ __launch_bounds__(256) void k_gather_init(
    const float* __restrict__ uw, const float* __restrict__ iw,
    const int* __restrict__ ui, const int* __restrict__ ii,
    float* __restrict__ out, int nq)
{
    int t = blockIdx.x * 256 + threadIdx.x;
    int total = nq * D;
    if (t < total) {
        int q = t >> 6, d = t & 63;
        out[t] = uw[ui[q] * D + d];
    } else if (t < 2 * total) {
        int u = t - total;
        int q = u >> 6, d = u & 63;
        out[t] = iw[ii[q] * D + d];
    }
}

__global__ __launch_bounds__(256) void k_gather_acc(
    const float* __restrict__ src,
    const int* __restrict__ ui, const int* __restrict__ ii,
    int n_users, float* __restrict__ out, int nq, float scale)
{
    int t = blockIdx.x * 256 + threadIdx.x;
    int total = nq * D;
    if (t < total) {
        int q = t >> 6, d = t & 63;
        int node = ui[q];
        out[t] = (out[t] + src[node * D + d]) * scale;
    } else if (t < 2 * total) {
        int u = t - total;
        int q = u >> 6, d = u & 63;
        int node = n_users + ii[q];
        out[t] = (out[t] + src[node * D + d]) * scale;
    }
}

// ============================== CSR build ===================================

__global__ __launch_bounds__(256) void k_count(
    const int* __restrict__ rows, int* __restrict__ cnt, int ne)
{
    int e = blockIdx.x * 256 + threadIdx.x;
    if (e < ne) atomicAdd(&cnt[rows[e]], 1);
}

// block-level exclusive scan over chunks of 1024, emit block sums
__global__ __launch_bounds__(1024) void k_scan1(
    const int* __restrict__ cnt, int* __restrict__ rstart,
    int* __restrict__ bsum, int n)
{
    __shared__ int s[1024];
    int t = threadIdx.x, i = blockIdx.x * 1024 + t;
    int v = (i < n) ? cnt[i] : 0;
    s[t] = v; __syncthreads();
    for (int off = 1; off < 1024; off <<= 1) {
        int x = (t >= off) ? s[t - off] : 0;
        __syncthreads();
        s[t] += x;
        __syncthreads();
    }
    if (i < n) rstart[i] = s[t] - v;             // exclusive within block
    if (t == 1023) bsum[blockIdx.x] = s[t];      // block total
}

// exclusive scan of the (<=1024) block sums, in place
__global__ __launch_bounds__(1024) void k_scan2(int* __restrict__ bsum, int nb)
{
    __shared__ int s[1024];
    int t = threadIdx.x;
    int v = (t < nb) ? bsum[t] : 0;
    s[t] = v; __syncthreads();
    for (int off = 1; off < 1024; off <<= 1) {
        int x = (t >= off) ? s[t - off] : 0;
        __syncthreads();
        s[t] += x;
        __syncthreads();
    }
    if (t < nb) bsum[t] = s[t] - v;
}

// finalize: rstart += block base, and duplicate into fill (scatter cursor)
__global__ __launch_bounds__(1024) void k_scan3(
    int* __restrict__ rstart, int* __restrict__ fill,
    const int* __restrict__ bsum, int n)
{
    int i = blockIdx.x * 1024 + threadIdx.x;
    if (i < n) {
        int v = rstart[i] + bsum[blockIdx.x];
        rstart[i] = v;
        fill[i] = v;
    }
}

// paired (col,val) scatter: ONE 8B store per edge instead of two 4B stores
__global__ __launch_bounds__(256) void k_scatter(
    const float* __restrict__ vals, const int* __restrict__ rows,
    const int* __restrict__ cols,
    int* __restrict__ fill, int2* __restrict__ cedge, int ne)
{
    int e = blockIdx.x * 256 + threadIdx.x;
    if (e < ne) {
        int r = rows[e];
        int p = atomicAdd(&fill[r], 1);          // absolute position
        int2 pk;
        pk.x = cols[e];
        pk.y = __float_as_int(vals[e]);
        cedge[p] = pk;
    }
}

// mark nodes whose layer-2 value is needed: Q itself and neighbors(Q)
__global__ __launch_bounds__(256) void k_mark(
    const int* __restrict__ rstart, const int* __restrict__ cnt,
    const int2* __restrict__ cedge,
    const int* __restrict__ ui, const int* __restrict__ ii,
    int n_users, unsigned char* __restrict__ flag, int nq)
{
    int q = blockIdx.x * 256 + threadIdx.x;
    if (q >= 2 * nq) return;
    int node = (q < nq) ? ui[q] : n_users + ii[q - nq];
    flag[node] = 1;
    int s = rstart[node], dg = cnt[node];
    for (int j = 0; j < dg; ++j) flag[cedge[s + j].x] = 1;
}

// ============================== CSR SpMM ====================================
// 16 lanes per row (float4 per lane), 16 rows per 256-thread block.
// flag != nullptr -> skip rows with flag==0 (their output is never read).
__global__ __launch_bounds__(256) void k_spmm_csr(
    const int* __restrict__ rstart, const int* __restrict__ cnt,
    const int2* __restrict__ cedge,
    const float* __restrict__ srcu, const float* __restrict__ srci,
    int n_users, float* __restrict__ dst, int n_nodes,
    const unsigned char* __restrict__ flag)
{
    int lane16 = threadIdx.x & 15;
    int row = blockIdx.x * 16 + (threadIdx.x >> 4);
    if (row >= n_nodes) return;
    if (flag && !flag[row]) return;

    int s = rstart[row], dg = cnt[row];
    float4 a0 = {0, 0, 0, 0}, a1 = {0, 0, 0, 0};
    int j = 0;
    for (; j + 1 < dg; j += 2) {
        int2 e0 = cedge[s + j], e1 = cedge[s + j + 1];
        int   c0 = e0.x,                 c1 = e1.x;
        float v0 = __int_as_float(e0.y), v1 = __int_as_float(e1.y);
        const float* p0 = (c0 < n_users) ? &srcu[(size_t)c0 * D] : &srci[(size_t)(c0 - n_users) * D];
        const float* p1 = (c1 < n_users) ? &srcu[(size_t)c1 * D] : &srci[(size_t)(c1 - n_users) * D];
        float4 x0 = ((const float4*)p0)[lane16];
        float4 x1 = ((const float4*)p1)[lane16];
        a0.x += v0 * x0.x; a0.y += v0 * x0.y; a0.z += v0 * x0.z; a0.w += v0 * x0.w;
        a1.x += v1 * x1.x; a1.y += v1 * x1.y; a1.z += v1 * x1.z; a1.w += v1 * x1.w;
    }
    if (j < dg) {
        int2 e0 = cedge[s + j];
        int c0 = e0.x; float v0 = __int_as_float(e0.y);
        const float* p0 = (c0 < n_users) ? &srcu[(size_t)c0 * D] : &srci[(size_t)(c0 - n_users) * D];
        float4 x0 = ((const float4*)p0)[lane16];
        a0.x += v0 * x0.x; a0.y += v0 * x0.y; a0.z += v0 * x0.z; a0.w += v0 * x0.w;
    }
    a0.x += a1.x; a0.y += a1.y; a0.z += a1.z; a0.w += a1.w;
    ((float4*)&dst[(size_t)row * D])[lane16] = a0;
}

// ======================= layer-3: per-query CSR walk ========================
__global__ __launch_bounds__(256) void k_final(
    const int* __restrict__ rstart, const int* __restrict__ cnt,
    const int2* __restrict__ cedge,
    const float* __restrict__ src,
    const int* __restrict__ ui, const int* __restrict__ ii,
    int n_users, float* __restrict__ out, int nq, float scale)
{
    int lane16 = threadIdx.x & 15;
    int q = blockIdx.x * 16 + (threadIdx.x >> 4);
    if (q >= 2 * nq) return;
    int node = (q < nq) ? ui[q] : n_users + ii[q - nq];

    int s = rstart[node], dg = cnt[node];
    float4 a0 = ((const float4*)&out[(size_t)q * D])[lane16];
    for (int j = 0; j < dg; ++j) {
        int2 e = cedge[s + j];
        int c = e.x; float v = __int_as_float(e.y);
        float4 x = ((const float4*)&src[(size_t)c * D])[lane16];
        a0.x += v * x.x; a0.y += v * x.y; a0.z += v * x.z; a0.w += v * x.w;
    }
    a0.x *= scale; a0.y *= scale; a0.z *= scale; a0.w *= scale;
    ((float4*)&out[(size_t)q * D])[lane16] = a0;
}

// ===================== fallback (round-2 atomic path) =======================

__global__ __launch_bounds__(256) void k_spmm_l0(
    const float* __restrict__ vals, const int* __restrict__ rows,
    const int* __restrict__ cols,
    const float* __restrict__ uw, const float* __restrict__ iw, int n_users,
    float* __restrict__ dst, int n_edges)
{
    int total = n_edges * D;
    int stride = gridDim.x * 256;
    for (int t = blockIdx.x * 256 + threadIdx.x; t < total; t += stride) {
        int e = t >> 6, d = t & 63;
        float v = vals[e];
        int c = cols[e], r = rows[e];
        float x = (c < n_users) ? uw[c * D + d] : iw[(c - n_users) * D + d];
        atomicAdd(dst + r * D + d, v * x);
    }
}

__global__ __launch_bounds__(256) void k_spmm(
    const float* __restrict__ vals, const int* __restrict__ rows,
    const int* __restrict__ cols,
    const float* __restrict__ src, float* __restrict__ dst, int n_edges)
{
    int total = n_edges * D;
    int stride = gridDim.x * 256;
    for (int t = blockIdx.x * 256 + threadIdx.x; t < total; t += stride) {
        int e = t >> 6, d = t & 63;
        float v = vals[e];
        int c = cols[e], r = rows[e];
        atomicAdd(dst + r * D + d, v * src[c * D + d]);
    }
}

// ============================================================================

extern "C" void kernel_launch(void* const* d_in, const int* in_sizes, int n_in,
                              void* d_out, int out_size, void* d_ws, size_t ws_size,
                              hipStream_t stream) {
    const float* uw   = (const float*)d_in[0];
    const float* iw   = (const float*)d_in[1];
    const float* vals = (const float*)d_in[2];
    const int*   rows = (const int*)d_in[3];
    const int*   cols = (const int*)d_in[4];
    const int*   ui   = (const int*)d_in[5];
    const int*   ii   = (const int*)d_in[6];
    float* out = (float*)d_out;

    const int n_users = in_sizes[0] / D;
    const int n_items = in_sizes[1] / D;
    const int n_nodes = n_users + n_items;
    const int n_edges = in_sizes[2];
    const int nq      = in_sizes[5];

    const size_t buf_elems = (size_t)n_nodes * D;

    // ---- workspace carve ----
    size_t off = 0;
    float* bufA   = (float*)((char*)d_ws + off); off += buf_elems * 4;
    float* bufB   = (float*)((char*)d_ws + off); off += buf_elems * 4;
    int*   cnt    = (int*)  ((char*)d_ws + off); off += (size_t)n_nodes * 4;
    int*   rstart = (int*)  ((char*)d_ws + off); off += (size_t)n_nodes * 4;
    int*   fill   = (int*)  ((char*)d_ws + off); off += (size_t)n_nodes * 4;
    int*   bsum   = (int*)  ((char*)d_ws + off); off += 4096 * 4;
    unsigned char* flag = (unsigned char*)((char*)d_ws + off);
    off += ((size_t)n_nodes + 255) & ~(size_t)255;
    int2*  cedge  = (int2*) ((char*)d_ws + off); off += (size_t)n_edges * 8;

    const int nblk_scan = (n_nodes + 1023) / 1024;
    const int gq = (2 * nq * D + 255) / 256;
    const bool csr_ok = (off <= ws_size) && (nblk_scan <= 1024);

    if (csr_ok) {
        // ---- CSR build ----
        hipMemsetAsync(cnt, 0, (size_t)n_nodes * 4, stream);
        hipMemsetAsync(flag, 0, (size_t)n_nodes, stream);
        k_count<<<(n_edges + 255) / 256, 256, 0, stream>>>(rows, cnt, n_edges);
        k_scan1<<<nblk_scan, 1024, 0, stream>>>(cnt, rstart, bsum, n_nodes);
        k_scan2<<<1, 1024, 0, stream>>>(bsum, nblk_scan);
        k_scan3<<<nblk_scan, 1024, 0, stream>>>(rstart, fill, bsum, n_nodes);
        k_scatter<<<(n_edges + 255) / 256, 256, 0, stream>>>(
            vals, rows, cols, fill, cedge, n_edges);

        // mark nodes whose layer-2 output is actually consumed
        k_mark<<<(2 * nq + 255) / 256, 256, 0, stream>>>(
            rstart, cnt, cedge, ui, ii, n_users, flag, nq);

        // ---- layer 0 gather ----
        k_gather_init<<<gq, 256, 0, stream>>>(uw, iw, ui, ii, out, nq);

        const int gs = (n_nodes + 15) / 16;
        // ---- layer 1: emb -> bufA (all rows) ----
        k_spmm_csr<<<gs, 256, 0, stream>>>(rstart, cnt, cedge,
                                           uw, iw, n_users, bufA, n_nodes, nullptr);
        k_gather_acc<<<gq, 256, 0, stream>>>(bufA, ui, ii, n_users, out, nq, 1.0f);

        // ---- layer 2: bufA -> bufB (marked rows only) ----
        k_spmm_csr<<<gs, 256, 0, stream>>>(rstart, cnt, cedge,
                                           bufA, bufA + (size_t)n_users * D,
                                           n_users, bufB, n_nodes, flag);
        k_gather_acc<<<gq, 256, 0, stream>>>(bufB, ui, ii, n_users, out, nq, 1.0f);

        // ---- layer 3: per-query only ----
        k_final<<<(2 * nq + 15) / 16, 256, 0, stream>>>(
            rstart, cnt, cedge, bufB, ui, ii, n_users, out, nq, 0.25f);
    } else {
        // ---- fallback: atomic path ----
        hipMemsetAsync(bufA, 0, 2 * buf_elems * 4, stream);
        const int gs = 8192;
        k_gather_init<<<gq, 256, 0, stream>>>(uw, iw, ui, ii, out, nq);
        k_spmm_l0<<<gs, 256, 0, stream>>>(vals, rows, cols, uw, iw, n_users, bufA, n_edges);
        k_gather_acc<<<gq, 256, 0, stream>>>(bufA, ui, ii, n_users, out, nq, 1.0f);
        k_spmm<<<gs, 256, 0, stream>>>(vals, rows, cols, bufA, bufB, n_edges);
        k_gather_acc<<<gq, 256, 0, stream>>>(bufB, ui, ii, n_users, out, nq, 1.0f);
        hipMemsetAsync(bufA, 0, buf_elems * 4, stream);
        k_spmm<<<gs, 256, 0, stream>>>(vals, rows, cols, bufB, bufA, n_edges);
        k_gather_acc<<<gq, 256, 0, stream>>>(bufA, ui, ii, n_users, out, nq, 0.25f);
    }
}